// Round 10
// baseline (270.986 us; speedup 1.0000x reference)
//
#include <hip/hip_runtime.h>

#define EPSV 1e-5f

typedef __attribute__((ext_vector_type(8))) short short8;
typedef __attribute__((ext_vector_type(4))) float f32x4;

__device__ __forceinline__ float softplus_f(float x){
    return fmaxf(x, 0.f) + log1pf(expf(-fabsf(x)));
}
__device__ __forceinline__ float bf2f(short u){
    union{unsigned int i; float f;} x; x.i = ((unsigned int)(unsigned short)u) << 16; return x.f;
}
__device__ __forceinline__ short f2bf(float f){
    union{float f; unsigned int i;} x; x.f = f;
    unsigned int r = x.i + 0x7fffu + ((x.i >> 16) & 1u);
    return (short)(r >> 16);
}

// =================== Level 1: fused x->bf16/deg/norm/gather + GEMM(128x64,K=64) ===================
// 512 blocks, 4 graphs each. Last block folds BN1 stats into scl1/sft1.
__global__ __launch_bounds__(256) void k_l1(const float* __restrict__ x, const float* __restrict__ ew,
        const float* __restrict__ W1a, const float* __restrict__ W1b, const float* __restrict__ b1,
        const float* __restrict__ g1, const float* __restrict__ be1,
        short* __restrict__ h1, float* __restrict__ gs, float* __restrict__ gq,
        int* __restrict__ cnt, float* __restrict__ scl1, float* __restrict__ sft1){
    __shared__ __align__(16) short A[128][72], T[128][72], Ba[64][72], Bb[64][72];
    __shared__ float ews[256], nrm[256], dinv[32], ssum[64], ssq[64];
    __shared__ int isLast;
    int blk = blockIdx.x, tid = threadIdx.x;
    if (tid < 64){ ssum[tid] = 0.f; ssq[tid] = 0.f; }
    // stage W1 (transpose + cvt): Ba[c][k] = bf16(W1a[k*64+c])
    for (int idx = tid; idx < 4096; idx += 256){
        int k = idx >> 6, c = idx & 63;
        Ba[c][k] = f2bf(W1a[idx]);
        Bb[c][k] = f2bf(W1b[idx]);
    }
    for (int gi = 0; gi < 4; ++gi){
        int g = blk*4 + gi;
        ews[tid] = ew[(size_t)g*256 + tid];
        const float4* xg = (const float4*)(x + (size_t)g*2048);
        #pragma unroll
        for (int q2 = 0; q2 < 2; ++q2){
            int i4 = tid + q2*256;
            int r = i4 >> 4, cc = (i4 & 15)*4;
            float4 v = xg[i4];
            A[gi*32+r][cc+0] = f2bf(v.x); A[gi*32+r][cc+1] = f2bf(v.y);
            A[gi*32+r][cc+2] = f2bf(v.z); A[gi*32+r][cc+3] = f2bf(v.w);
        }
        __syncthreads();
        if (tid < 32){
            float d = 0.f;
            #pragma unroll
            for (int k = 0; k < 8; ++k) d += ews[tid*8 + k];
            dinv[tid] = d > 0.f ? rsqrtf(d) : 0.f;
        }
        __syncthreads();
        {   int se = tid >> 3, de = (se + (tid & 7) + 1) & 31;
            nrm[tid] = -dinv[se] * ews[tid] * dinv[de]; }
        __syncthreads();
        {   int v = tid >> 3, ch = (tid & 7)*8;
            float acc[8];
            #pragma unroll
            for (int j = 0; j < 8; ++j) acc[j] = 0.f;
            #pragma unroll
            for (int k = 0; k < 8; ++k){
                int sl = (v - k - 1) & 31;
                float nw = nrm[sl*8 + k];
                short8 xv = *(const short8*)&A[gi*32 + sl][ch];
                #pragma unroll
                for (int j = 0; j < 8; ++j) acc[j] = fmaf(nw, bf2f(xv[j]), acc[j]);
            }
            short8 o;
            #pragma unroll
            for (int j = 0; j < 8; ++j) o[j] = f2bf(acc[j]);
            *(short8*)&T[gi*32 + v][ch] = o;
        }
        __syncthreads();
    }
    // MFMA: 4 waves, RPW=32 (RT=2), CT=4
    int lane = tid & 63, w = tid >> 6, lrow = lane & 15, lk8 = lane >> 4;
    f32x4 acc[2][4];
    #pragma unroll
    for (int rt = 0; rt < 2; ++rt)
        #pragma unroll
        for (int ct = 0; ct < 4; ++ct) acc[rt][ct] = (f32x4){0,0,0,0};
    typedef short row72[72];
    #pragma unroll
    for (int seg = 0; seg < 2; ++seg){
        row72* Ag = seg ? T : A;
        row72* Bg = seg ? Bb : Ba;
        #pragma unroll
        for (int ks = 0; ks < 2; ++ks){
            short8 af[2];
            #pragma unroll
            for (int rt = 0; rt < 2; ++rt)
                af[rt] = *(const short8*)&Ag[w*32 + rt*16 + lrow][ks*32 + lk8*8];
            #pragma unroll
            for (int ct = 0; ct < 4; ++ct){
                short8 bf = *(const short8*)&Bg[ct*16 + lrow][ks*32 + lk8*8];
                #pragma unroll
                for (int rt = 0; rt < 2; ++rt)
                    acc[rt][ct] = __builtin_amdgcn_mfma_f32_16x16x32_bf16(af[rt], bf, acc[rt][ct], 0, 0, 0);
            }
        }
    }
    #pragma unroll
    for (int ct = 0; ct < 4; ++ct){
        int col = ct*16 + lrow;
        float bb = b1[col];
        float s = 0.f, q = 0.f;
        #pragma unroll
        for (int rt = 0; rt < 2; ++rt){
            #pragma unroll
            for (int e = 0; e < 4; ++e){
                float v = acc[rt][ct][e] + bb;
                int row = blk*128 + w*32 + rt*16 + lk8*4 + e;
                h1[(size_t)row*64 + col] = f2bf(v);
                s += v; q += v*v;
            }
        }
        s += __shfl_xor(s, 16); s += __shfl_xor(s, 32);
        q += __shfl_xor(q, 16); q += __shfl_xor(q, 32);
        if (lane < 16){ atomicAdd(&ssum[col], s); atomicAdd(&ssq[col], q); }
    }
    __syncthreads();
    if (tid < 64){ atomicAdd(&gs[tid], ssum[tid]); atomicAdd(&gq[tid], ssq[tid]); }
    __syncthreads();            // drains vmcnt: global atomics complete before counter
    if (tid == 0) isLast = (atomicAdd(cnt, 1) == 511);
    __syncthreads();
    if (isLast && tid < 64){
        float s = atomicAdd(&gs[tid], 0.f);   // coherent read
        float q = atomicAdd(&gq[tid], 0.f);
        float m = s * (1.f/65536.f);
        float var = q * (1.f/65536.f) - m*m;
        float rs = rsqrtf(var + EPSV) * g1[tid];
        scl1[tid] = rs; sft1[tid] = be1[tid] - m*rs;
    }
}

// =================== Level 2: fused BN1/pool/deg/norm/gather + GEMM(64x128,K=64) ===================
// 512 blocks, 4 graphs each (16 pooled rows per graph).
__global__ __launch_bounds__(256) void k_l2(const short* __restrict__ h1, const float* __restrict__ ew,
        const float* __restrict__ scl1, const float* __restrict__ sft1,
        const float* __restrict__ W2a, const float* __restrict__ W2b, const float* __restrict__ b2,
        const float* __restrict__ g2, const float* __restrict__ be2,
        short* __restrict__ h2, float* __restrict__ gs, float* __restrict__ gq,
        int* __restrict__ cnt, float* __restrict__ scl2, float* __restrict__ sft2){
    __shared__ __align__(16) short A[64][72], T[64][72], Ba[128][72], Bb[128][72];
    __shared__ float ews[256], nrm[256], dinv[16], sscl[64], ssft[64], ssum[128], ssq[128];
    __shared__ int isLast;
    int blk = blockIdx.x, tid = threadIdx.x;
    if (tid < 128){ ssum[tid] = 0.f; ssq[tid] = 0.f; }
    if (tid < 64){ sscl[tid] = scl1[tid]; ssft[tid] = sft1[tid]; }
    for (int idx = tid; idx < 8192; idx += 256){
        int k = idx >> 7, c = idx & 127;
        Ba[c][k] = f2bf(W2a[idx]);
        Bb[c][k] = f2bf(W2b[idx]);
    }
    __syncthreads();
    for (int gi = 0; gi < 4; ++gi){
        int g = blk*4 + gi;
        ews[tid] = ew[(size_t)g*256 + tid];
        __syncthreads();
        if (tid < 128){
            int vo = tid >> 3, ch = (tid & 7)*8;
            short8 a = *(const short8*)&h1[((size_t)g*32 + 2*vo)*64 + ch];
            short8 b = *(const short8*)&h1[((size_t)g*32 + 2*vo + 1)*64 + ch];
            short8 o;
            #pragma unroll
            for (int j = 0; j < 8; ++j){
                float s = sscl[ch+j], t = ssft[ch+j];
                float va = softplus_f(bf2f(a[j])*s + t);
                float vb = softplus_f(bf2f(b[j])*s + t);
                o[j] = f2bf(fmaxf(va, vb));
            }
            *(short8*)&A[gi*16 + vo][ch] = o;
        }
        if (tid < 16){
            float d = 0.f;
            for (int t = tid*16; t < tid*16 + 16; ++t){
                int se = t >> 3, de = (se + (t & 7) + 1) & 31;
                float wv = ((se >> 1) == (de >> 1)) ? 0.f : ews[t];
                d += wv;
            }
            dinv[tid] = d > 0.f ? rsqrtf(d) : 0.f;
        }
        __syncthreads();
        {   int se = tid >> 3, de = (se + (tid & 7) + 1) & 31;
            float wv = ((se >> 1) == (de >> 1)) ? 0.f : ews[tid];
            nrm[tid] = -dinv[se >> 1] * wv * dinv[de >> 1]; }
        __syncthreads();
        if (tid < 128){
            int v = tid >> 3, ch = (tid & 7)*8;
            float acc[8];
            #pragma unroll
            for (int j = 0; j < 8; ++j) acc[j] = 0.f;
            #pragma unroll
            for (int dd = 0; dd < 2; ++dd){
                int d = v*2 + dd;
                #pragma unroll
                for (int k = 0; k < 8; ++k){
                    int sl = (d - k - 1) & 31;
                    float nw = nrm[sl*8 + k];
                    short8 xv = *(const short8*)&A[gi*16 + (sl >> 1)][ch];
                    #pragma unroll
                    for (int j = 0; j < 8; ++j) acc[j] = fmaf(nw, bf2f(xv[j]), acc[j]);
                }
            }
            short8 o;
            #pragma unroll
            for (int j = 0; j < 8; ++j) o[j] = f2bf(acc[j]);
            *(short8*)&T[gi*16 + v][ch] = o;
        }
        __syncthreads();
    }
    int lane = tid & 63, w = tid >> 6, lrow = lane & 15, lk8 = lane >> 4;
    f32x4 acc[8];
    #pragma unroll
    for (int ct = 0; ct < 8; ++ct) acc[ct] = (f32x4){0,0,0,0};
    typedef short row72[72];
    #pragma unroll
    for (int seg = 0; seg < 2; ++seg){
        row72* Ag = seg ? T : A;
        row72* Bg = seg ? Bb : Ba;
        #pragma unroll
        for (int ks = 0; ks < 2; ++ks){
            short8 af = *(const short8*)&Ag[w*16 + lrow][ks*32 + lk8*8];
            #pragma unroll
            for (int ct = 0; ct < 8; ++ct){
                short8 bf = *(const short8*)&Bg[ct*16 + lrow][ks*32 + lk8*8];
                acc[ct] = __builtin_amdgcn_mfma_f32_16x16x32_bf16(af, bf, acc[ct], 0, 0, 0);
            }
        }
    }
    #pragma unroll
    for (int ct = 0; ct < 8; ++ct){
        int col = ct*16 + lrow;
        float bb = b2[col];
        float s = 0.f, q = 0.f;
        #pragma unroll
        for (int e = 0; e < 4; ++e){
            float v = acc[ct][e] + bb;
            int row = blk*64 + w*16 + lk8*4 + e;
            h2[(size_t)row*128 + col] = f2bf(v);
            s += v; q += v*v;
        }
        s += __shfl_xor(s, 16); s += __shfl_xor(s, 32);
        q += __shfl_xor(q, 16); q += __shfl_xor(q, 32);
        if (lane < 16){ atomicAdd(&ssum[col], s); atomicAdd(&ssq[col], q); }
    }
    __syncthreads();
    if (tid < 128){ atomicAdd(&gs[tid], ssum[tid]); atomicAdd(&gq[tid], ssq[tid]); }
    __syncthreads();
    if (tid == 0) isLast = (atomicAdd(cnt, 1) == 511);
    __syncthreads();
    if (isLast && tid < 128){
        float s = atomicAdd(&gs[tid], 0.f);
        float q = atomicAdd(&gq[tid], 0.f);
        float m = s * (1.f/32768.f);
        float var = q * (1.f/32768.f) - m*m;
        float rs = rsqrtf(var + EPSV) * g2[tid];
        scl2[tid] = rs; sft2[tid] = be2[tid] - m*rs;
    }
}

// =================== Level 3: fused BN2/pool/deg/norm/gather + GEMM(64x128,K=128, 2 col-chunks) ===================
// 256 blocks, 8 graphs each (8 pooled rows per graph).
__global__ __launch_bounds__(256) void k_l3(const short* __restrict__ h2, const float* __restrict__ ew,
        const float* __restrict__ scl2, const float* __restrict__ sft2,
        const float* __restrict__ W3a, const float* __restrict__ W3b, const float* __restrict__ b3,
        const float* __restrict__ g3, const float* __restrict__ be3,
        short* __restrict__ h3, float* __restrict__ gs, float* __restrict__ gq,
        int* __restrict__ cnt, float* __restrict__ scl3, float* __restrict__ sft3){
    __shared__ __align__(16) short A[64][136], T[64][136], Ba[64][136], Bb[64][136];
    __shared__ float ews[256], nrm[256], dinv[8], sscl[128], ssft[128], ssum[128], ssq[128];
    __shared__ int isLast;
    int blk = blockIdx.x, tid = threadIdx.x;
    if (tid < 128){ ssum[tid] = 0.f; ssq[tid] = 0.f; sscl[tid] = scl2[tid]; ssft[tid] = sft2[tid]; }
    __syncthreads();
    for (int gi = 0; gi < 8; ++gi){
        int g = blk*8 + gi;
        ews[tid] = ew[(size_t)g*256 + tid];
        __syncthreads();
        if (tid < 128){
            int vo = tid >> 4, ch = (tid & 15)*8;
            short8 a = *(const short8*)&h2[((size_t)g*16 + 2*vo)*128 + ch];
            short8 b = *(const short8*)&h2[((size_t)g*16 + 2*vo + 1)*128 + ch];
            short8 o;
            #pragma unroll
            for (int j = 0; j < 8; ++j){
                float s = sscl[ch+j], t = ssft[ch+j];
                float va = softplus_f(bf2f(a[j])*s + t);
                float vb = softplus_f(bf2f(b[j])*s + t);
                o[j] = f2bf(fmaxf(va, vb));
            }
            *(short8*)&A[gi*8 + vo][ch] = o;
        }
        if (tid < 8){
            float d = 0.f;
            for (int t = tid*32; t < tid*32 + 32; ++t){
                int se = t >> 3, de = (se + (t & 7) + 1) & 31;
                float wv = ((se >> 2) == (de >> 2)) ? 0.f : ews[t];
                d += wv;
            }
            dinv[tid] = d > 0.f ? rsqrtf(d) : 0.f;
        }
        __syncthreads();
        {   int se = tid >> 3, de = (se + (tid & 7) + 1) & 31;
            float wv = ((se >> 2) == (de >> 2)) ? 0.f : ews[tid];
            nrm[tid] = -dinv[se >> 2] * wv * dinv[de >> 2]; }
        __syncthreads();
        if (tid < 128){
            int v = tid >> 4, ch = (tid & 15)*8;
            float acc[8];
            #pragma unroll
            for (int j = 0; j < 8; ++j) acc[j] = 0.f;
            #pragma unroll
            for (int dd = 0; dd < 4; ++dd){
                int d = v*4 + dd;
                #pragma unroll
                for (int k = 0; k < 8; ++k){
                    int sl = (d - k - 1) & 31;
                    float nw = nrm[sl*8 + k];
                    short8 xv = *(const short8*)&A[gi*8 + (sl >> 2)][ch];
                    #pragma unroll
                    for (int j = 0; j < 8; ++j) acc[j] = fmaf(nw, bf2f(xv[j]), acc[j]);
                }
            }
            short8 o;
            #pragma unroll
            for (int j = 0; j < 8; ++j) o[j] = f2bf(acc[j]);
            *(short8*)&T[gi*8 + v][ch] = o;
        }
        __syncthreads();
    }
    int lane = tid & 63, w = tid >> 6, lrow = lane & 15, lk8 = lane >> 4;
    typedef short row136[136];
    #pragma unroll
    for (int cc = 0; cc < 2; ++cc){
        __syncthreads();
        for (int idx = tid; idx < 8192; idx += 256){
            int k = idx >> 6, c = idx & 63;
            Ba[c][k] = f2bf(W3a[(size_t)k*128 + cc*64 + c]);
            Bb[c][k] = f2bf(W3b[(size_t)k*128 + cc*64 + c]);
        }
        __syncthreads();
        f32x4 acc[4];
        #pragma unroll
        for (int ct = 0; ct < 4; ++ct) acc[ct] = (f32x4){0,0,0,0};
        #pragma unroll
        for (int seg = 0; seg < 2; ++seg){
            row136* Ag = seg ? T : A;
            row136* Bg = seg ? Bb : Ba;
            #pragma unroll
            for (int ks = 0; ks < 4; ++ks){
                short8 af = *(const short8*)&Ag[w*16 + lrow][ks*32 + lk8*8];
                #pragma unroll
                for (int ct = 0; ct < 4; ++ct){
                    short8 bf = *(const short8*)&Bg[ct*16 + lrow][ks*32 + lk8*8];
                    acc[ct] = __builtin_amdgcn_mfma_f32_16x16x32_bf16(af, bf, acc[ct], 0, 0, 0);
                }
            }
        }
        #pragma unroll
        for (int ct = 0; ct < 4; ++ct){
            int col = cc*64 + ct*16 + lrow;
            float bb = b3[col];
            float s = 0.f, q = 0.f;
            #pragma unroll
            for (int e = 0; e < 4; ++e){
                float v = acc[ct][e] + bb;
                int row = blk*64 + w*16 + lk8*4 + e;
                h3[(size_t)row*128 + col] = f2bf(v);
                s += v; q += v*v;
            }
            s += __shfl_xor(s, 16); s += __shfl_xor(s, 32);
            q += __shfl_xor(q, 16); q += __shfl_xor(q, 32);
            if (lane < 16){ atomicAdd(&ssum[col], s); atomicAdd(&ssq[col], q); }
        }
    }
    __syncthreads();
    if (tid < 128){ atomicAdd(&gs[tid], ssum[tid]); atomicAdd(&gq[tid], ssq[tid]); }
    __syncthreads();
    if (tid == 0) isLast = (atomicAdd(cnt, 1) == 255);
    __syncthreads();
    if (isLast && tid < 128){
        float s = atomicAdd(&gs[tid], 0.f);
        float q = atomicAdd(&gq[tid], 0.f);
        float m = s * (1.f/16384.f);
        float var = q * (1.f/16384.f) - m*m;
        float rs = rsqrtf(var + EPSV) * g3[tid];
        scl3[tid] = rs; sft3[tid] = be3[tid] - m*rs;
    }
}

// =================== head: BN3+softplus+mean+FC+log_softmax, one wave per graph ===================
__global__ __launch_bounds__(256) void k_head(const short* __restrict__ h3,
        const float* __restrict__ scl3, const float* __restrict__ sft3,
        const float* __restrict__ fcW, const float* __restrict__ fcb,
        float* __restrict__ out){
    int tid = threadIdx.x, w = tid >> 6, lane = tid & 63;
    int g = blockIdx.x*4 + w;
    int c0 = lane*2;
    float sc0 = scl3[c0], sh0 = sft3[c0];
    float sc1 = scl3[c0+1], sh1 = sft3[c0+1];
    float acc0 = 0.f, acc1 = 0.f;
    #pragma unroll
    for (int n = 0; n < 8; ++n){
        unsigned int v = *(const unsigned int*)&h3[((size_t)g*8 + n)*128 + c0];
        union{unsigned int i; float f;} lo, hi;
        lo.i = v << 16; hi.i = v & 0xffff0000u;
        acc0 += softplus_f(lo.f*sc0 + sh0);
        acc1 += softplus_f(hi.f*sc1 + sh1);
    }
    float hg0 = acc0 * 0.125f, hg1 = acc1 * 0.125f;
    float4 w0 = ((const float4*)fcW)[c0];
    float4 w1 = ((const float4*)fcW)[c0+1];
    float z0 = hg0*w0.x + hg1*w1.x;
    float z1 = hg0*w0.y + hg1*w1.y;
    float z2 = hg0*w0.z + hg1*w1.z;
    float z3 = hg0*w0.w + hg1*w1.w;
    #pragma unroll
    for (int d = 1; d < 64; d <<= 1){
        z0 += __shfl_xor(z0, d); z1 += __shfl_xor(z1, d);
        z2 += __shfl_xor(z2, d); z3 += __shfl_xor(z3, d);
    }
    if (lane == 0){
        z0 += fcb[0]; z1 += fcb[1]; z2 += fcb[2]; z3 += fcb[3];
        float mx = fmaxf(fmaxf(z0, z1), fmaxf(z2, z3));
        float lse = mx + logf(expf(z0-mx) + expf(z1-mx) + expf(z2-mx) + expf(z3-mx));
        *(float4*)(out + (size_t)g*4) = make_float4(z0-lse, z1-lse, z2-lse, z3-lse);
    }
}

extern "C" void kernel_launch(void* const* d_in, const int* in_sizes, int n_in,
                              void* d_out, int out_size, void* d_ws, size_t ws_size,
                              hipStream_t stream){
    const float* x   = (const float*)d_in[0];
    const float* ew  = (const float*)d_in[1];
    const float* W1a = (const float*)d_in[2];
    const float* W1b = (const float*)d_in[3];
    const float* b1  = (const float*)d_in[4];
    const float* g1  = (const float*)d_in[5];
    const float* be1 = (const float*)d_in[6];
    const float* W2a = (const float*)d_in[7];
    const float* W2b = (const float*)d_in[8];
    const float* b2  = (const float*)d_in[9];
    const float* g2  = (const float*)d_in[10];
    const float* be2 = (const float*)d_in[11];
    const float* W3a = (const float*)d_in[12];
    const float* W3b = (const float*)d_in[13];
    const float* b3  = (const float*)d_in[14];
    const float* g3  = (const float*)d_in[15];
    const float* be3 = (const float*)d_in[16];
    const float* fcW = (const float*)d_in[17];
    const float* fcb = (const float*)d_in[18];
    float* out = (float*)d_out;
    (void)in_sizes; (void)n_in; (void)out_size; (void)ws_size;

    short* h1 = (short*)d_ws;                    // 65536*64  bf16
    short* h2 = h1 + (size_t)4194304;            // 32768*128 bf16
    short* h3 = h2 + (size_t)4194304;            // 16384*128 bf16
    float* fp = (float*)(((uintptr_t)(h3 + 2097152) + 255) & ~(uintptr_t)255);
    int*   cnt1 = (int*)(fp + 0);
    int*   cnt2 = (int*)(fp + 1);
    int*   cnt3 = (int*)(fp + 2);
    float* gs1 = fp + 4;    float* gq1 = fp + 68;     // 64 + 64
    float* gs2 = fp + 132;  float* gq2 = fp + 260;    // 128 + 128
    float* gs3 = fp + 388;  float* gq3 = fp + 516;    // 128 + 128
    float* scl1 = fp + 644; float* sft1 = fp + 708;
    float* scl2 = fp + 772; float* sft2 = fp + 900;
    float* scl3 = fp + 1028; float* sft3 = fp + 1156; // end 1284

    hipMemsetAsync(fp, 0, 644*sizeof(float), stream);   // counters + stat accumulators

    k_l1<<<512, 256, 0, stream>>>(x, ew, W1a, W1b, b1, g1, be1,
                                  h1, gs1, gq1, cnt1, scl1, sft1);
    k_l2<<<512, 256, 0, stream>>>(h1, ew, scl1, sft1, W2a, W2b, b2, g2, be2,
                                  h2, gs2, gq2, cnt2, scl2, sft2);
    k_l3<<<256, 256, 0, stream>>>(h2, ew, scl2, sft2, W3a, W3b, b3, g3, be3,
                                  h3, gs3, gq3, cnt3, scl3, sft3);
    k_head<<<512, 256, 0, stream>>>(h3, scl3, sft3, fcW, fcb, out);
}